// Round 2
// baseline (1175.301 us; speedup 1.0000x reference)
//
#include <hip/hip_runtime.h>

#define N_NODES 100000
#define N_EDGES 600000
#define D 128
#define RPB 32     // rows per block in fused matmul
#define PAD 36     // LDS row pad (floats): 36*4=144B keeps float4 alignment, spreads banks

// ---------------- W transpose: Wt[k][j] = W[j][k] ----------------
__global__ __launch_bounds__(256) void transpose_w(const float* __restrict__ Ws,
                                                   const float* __restrict__ Wn,
                                                   float* __restrict__ Wts,
                                                   float* __restrict__ Wtn) {
    int t = blockIdx.x * 256 + threadIdx.x;   // 0..16383
    int j = t & (D - 1);
    int k = t >> 7;
    Wts[t] = Ws[j * D + k];
    Wtn[t] = Wn[j * D + k];
}

// ---------------- edge scatter: agg[dst] += x[src]; deg[dst] += 1 ----------------
__global__ __launch_bounds__(256) void scatter_edges(const float* __restrict__ x,
                                                     const int* __restrict__ src,
                                                     const int* __restrict__ dst,
                                                     float* __restrict__ agg,
                                                     float* __restrict__ deg) {
    long long gid = (long long)blockIdx.x * 256 + threadIdx.x;
    int e = (int)(gid >> 5);        // 32 threads per edge
    int q = (int)(gid & 31);        // each thread handles 4 consecutive features
    if (e >= N_EDGES) return;
    int s = src[e];
    int d = dst[e];
    float4 v = *reinterpret_cast<const float4*>(x + (size_t)s * D + q * 4);
    float* a = agg + (size_t)d * D + q * 4;
    unsafeAtomicAdd(a + 0, v.x);
    unsafeAtomicAdd(a + 1, v.y);
    unsafeAtomicAdd(a + 2, v.z);
    unsafeAtomicAdd(a + 3, v.w);
    if (q == 0) unsafeAtomicAdd(deg + d, 1.0f);
}

// ---------------- fused: h = x@Ws^T + (agg/deg)@Wn^T + b, relu ----------------
// agg aliases out (same buffer): each block reads its own 32 rows of agg before
// writing its own 32 rows of h — no cross-block overlap.
__global__ __launch_bounds__(256) void fused_sage(const float* __restrict__ x,
                                                  const float* __restrict__ agg,
                                                  const float* __restrict__ deg,
                                                  const float* __restrict__ Wts,
                                                  const float* __restrict__ Wtn,
                                                  const float* __restrict__ bs,
                                                  const float* __restrict__ bn,
                                                  float* __restrict__ out) {
    __shared__ float xs[D * PAD];   // transposed tile: xs[k*PAD + r]
    __shared__ float as_[D * PAD];  // pre-scaled agg tile, transposed

    int tid = threadIdx.x;
    int row0 = blockIdx.x * RPB;

    // ---- stage 32 rows of x and agg (scaled by 1/max(deg,1)) transposed into LDS
    int r  = tid >> 3;           // 0..31 : row within tile
    int c0 = (tid & 7) * 4;      // 0..28 : starting col of this thread's float4
    float scale = 1.0f / fmaxf(deg[row0 + r], 1.0f);
    #pragma unroll
    for (int it = 0; it < 4; ++it) {
        int c = c0 + it * 32;
        float4 xv = *reinterpret_cast<const float4*>(x   + (size_t)(row0 + r) * D + c);
        float4 av = *reinterpret_cast<const float4*>(agg + (size_t)(row0 + r) * D + c);
        xs[(c + 0) * PAD + r] = xv.x;
        xs[(c + 1) * PAD + r] = xv.y;
        xs[(c + 2) * PAD + r] = xv.z;
        xs[(c + 3) * PAD + r] = xv.w;
        as_[(c + 0) * PAD + r] = av.x * scale;
        as_[(c + 1) * PAD + r] = av.y * scale;
        as_[(c + 2) * PAD + r] = av.z * scale;
        as_[(c + 3) * PAD + r] = av.w * scale;
    }
    __syncthreads();

    // ---- 4x4 register tile per thread: rows rg*4.., cols cg*4..
    int cg = tid & 31;
    int rg = tid >> 5;
    float acc[4][4] = {};

    const float4* wtsv = reinterpret_cast<const float4*>(Wts);  // [k][32] float4s
    const float4* wtnv = reinterpret_cast<const float4*>(Wtn);

    #pragma unroll 4
    for (int k = 0; k < D; ++k) {
        float4 xv = *reinterpret_cast<const float4*>(&xs[k * PAD + rg * 4]);
        float4 av = *reinterpret_cast<const float4*>(&as_[k * PAD + rg * 4]);
        float4 ws = wtsv[k * 32 + cg];
        float4 wn = wtnv[k * 32 + cg];
        float xr[4]  = {xv.x, xv.y, xv.z, xv.w};
        float ar[4]  = {av.x, av.y, av.z, av.w};
        float wsr[4] = {ws.x, ws.y, ws.z, ws.w};
        float wnr[4] = {wn.x, wn.y, wn.z, wn.w};
        #pragma unroll
        for (int qq = 0; qq < 4; ++qq)
            #pragma unroll
            for (int cc = 0; cc < 4; ++cc)
                acc[qq][cc] += xr[qq] * wsr[cc] + ar[qq] * wnr[cc];
    }

    float4 bsv = *reinterpret_cast<const float4*>(bs + cg * 4);
    float4 bnv = *reinterpret_cast<const float4*>(bn + cg * 4);
    float bias[4] = {bsv.x + bnv.x, bsv.y + bnv.y, bsv.z + bnv.z, bsv.w + bnv.w};

    #pragma unroll
    for (int qq = 0; qq < 4; ++qq) {
        float4 o;
        o.x = fmaxf(acc[qq][0] + bias[0], 0.0f);
        o.y = fmaxf(acc[qq][1] + bias[1], 0.0f);
        o.z = fmaxf(acc[qq][2] + bias[2], 0.0f);
        o.w = fmaxf(acc[qq][3] + bias[3], 0.0f);
        *reinterpret_cast<float4*>(out + (size_t)(row0 + rg * 4 + qq) * D + cg * 4) = o;
    }
}

extern "C" void kernel_launch(void* const* d_in, const int* in_sizes, int n_in,
                              void* d_out, int out_size, void* d_ws, size_t ws_size,
                              hipStream_t stream) {
    const float* x  = (const float*)d_in[0];
    const int*   ei = (const int*)d_in[1];   // [2][600000]: row0=src, row1=dst
    const float* Ws = (const float*)d_in[2];
    const float* bs = (const float*)d_in[3];
    const float* Wn = (const float*)d_in[4];
    const float* bn = (const float*)d_in[5];
    float* out = (float*)d_out;

    const int* src = ei;
    const int* dst = ei + N_EDGES;

    // d_ws layout (needs 528 KB): deg[100000] f32 | Wts[128*128] f32 | Wtn[128*128] f32
    float* deg = (float*)d_ws;                 // 400 KB
    float* Wts = (float*)d_ws + N_NODES;       // 64 KB, 16B-aligned (400000 % 16 == 0)
    float* Wtn = Wts + D * D;                  // 64 KB

    // zero agg (accumulated in d_out) and deg
    hipMemsetAsync(d_out, 0, (size_t)N_NODES * D * sizeof(float), stream);
    hipMemsetAsync(deg, 0, N_NODES * sizeof(float), stream);

    transpose_w<<<(D * D) / 256, 256, 0, stream>>>(Ws, Wn, Wts, Wtn);
    scatter_edges<<<(N_EDGES * 32) / 256, 256, 0, stream>>>(x, src, dst, out, deg);
    fused_sage<<<N_NODES / RPB, 256, 0, stream>>>(x, out, deg, Wts, Wtn, bs, bn, out);
}

// Round 4
// 221.522 us; speedup vs baseline: 5.3056x; 5.3056x over previous
//
#include <hip/hip_runtime.h>

#define N_NODES 100000
#define N_EDGES 600000
#define D 128
#define RPB 32      // rows per block in fused kernel (100000/32 = 3125 exact)
#define PAD 36      // LDS row pad (floats); keeps 16B alignment for float4 reads
#define SCAN_BLK 256
#define NB1 ((N_NODES + SCAN_BLK - 1) / SCAN_BLK)   // 391

// ---------------- W transpose: Wt[k][j] = W[j][k] ----------------
__global__ __launch_bounds__(256) void transpose_w(const float* __restrict__ Ws,
                                                   const float* __restrict__ Wn,
                                                   float* __restrict__ Wts,
                                                   float* __restrict__ Wtn) {
    int t = blockIdx.x * 256 + threadIdx.x;   // 0..16383
    int j = t & (D - 1);
    int k = t >> 7;
    Wts[t] = Ws[j * D + k];
    Wtn[t] = Wn[j * D + k];
}

// ================= CSR build =================
__global__ __launch_bounds__(256) void count_deg(const int* __restrict__ dst,
                                                 int* __restrict__ deg) {
    int e = blockIdx.x * 256 + threadIdx.x;
    if (e < N_EDGES) atomicAdd(&deg[dst[e]], 1);
}

__global__ __launch_bounds__(SCAN_BLK) void scan1(const int* __restrict__ deg,
                                                  int* __restrict__ offs,
                                                  int* __restrict__ bsum) {
    __shared__ int sh[SCAN_BLK];
    int t = threadIdx.x;
    int i = blockIdx.x * SCAN_BLK + t;
    int v = (i < N_NODES) ? deg[i] : 0;
    sh[t] = v;
    __syncthreads();
    for (int off = 1; off < SCAN_BLK; off <<= 1) {
        int add = (t >= off) ? sh[t - off] : 0;
        __syncthreads();
        sh[t] += add;
        __syncthreads();
    }
    if (i < N_NODES) offs[i] = sh[t] - v;          // block-local exclusive
    if (t == SCAN_BLK - 1) bsum[blockIdx.x] = sh[t];
}

__global__ __launch_bounds__(512) void scan2(int* __restrict__ bsum) {
    __shared__ int sh[512];
    int t = threadIdx.x;
    int v = (t < NB1) ? bsum[t] : 0;
    sh[t] = v;
    __syncthreads();
    for (int off = 1; off < 512; off <<= 1) {
        int add = (t >= off) ? sh[t - off] : 0;
        __syncthreads();
        sh[t] += add;
        __syncthreads();
    }
    if (t < NB1) bsum[t] = sh[t] - v;              // exclusive
}

// finalize offsets; init cursor (aliases deg — deg is dead after scan1)
__global__ __launch_bounds__(SCAN_BLK) void scan3(int* __restrict__ offs,
                                                  const int* __restrict__ bsum,
                                                  int* __restrict__ cursor) {
    int i = blockIdx.x * SCAN_BLK + threadIdx.x;
    if (i < N_NODES) {
        int o = offs[i] + bsum[blockIdx.x];
        offs[i] = o;
        cursor[i] = o;
    }
    if (i == 0) offs[N_NODES] = N_EDGES;
}

__global__ __launch_bounds__(256) void fill_csr(const int* __restrict__ src,
                                                const int* __restrict__ dst,
                                                int* __restrict__ cursor,
                                                int* __restrict__ csr_src) {
    int e = blockIdx.x * 256 + threadIdx.x;
    if (e < N_EDGES) {
        int pos = atomicAdd(&cursor[dst[e]], 1);
        csr_src[pos] = src[e];
    }
}

// ================= fused gather-aggregate + matmul + bias + relu =================
// h = x@Ws^T + (mean_neigh)@Wn^T + bs + bn, relu. No global agg buffer.
__global__ __launch_bounds__(256) void fused_sage_csr(const float* __restrict__ x,
                                                      const int* __restrict__ offs,
                                                      const int* __restrict__ csr_src,
                                                      const float* __restrict__ Wts,
                                                      const float* __restrict__ Wtn,
                                                      const float* __restrict__ bs,
                                                      const float* __restrict__ bn,
                                                      float* __restrict__ out) {
    __shared__ float xs[D * PAD];   // transposed: xs[k*PAD + r]
    __shared__ float as_[D * PAD];  // mean-aggregated tile, transposed

    int tid = threadIdx.x;
    int row0 = blockIdx.x * RPB;

    // ---- phase A: stage 32 rows of x transposed
    {
        int r  = tid >> 3;
        int c0 = (tid & 7) * 4;
        #pragma unroll
        for (int it = 0; it < 4; ++it) {
            int c = c0 + it * 32;
            float4 xv = *reinterpret_cast<const float4*>(x + (size_t)(row0 + r) * D + c);
            xs[(c + 0) * PAD + r] = xv.x;
            xs[(c + 1) * PAD + r] = xv.y;
            xs[(c + 2) * PAD + r] = xv.z;
            xs[(c + 3) * PAD + r] = xv.w;
        }
    }

    // ---- phase B: gather-aggregate neighbors, registers only
    {
        int hw = tid >> 5;      // half-wave id 0..7
        int l  = tid & 31;      // lane-in-half-wave; handles feats l*4..l*4+3
        #pragma unroll
        for (int i = 0; i < 4; ++i) {
            int rr = hw * 4 + i;
            int v  = row0 + rr;
            int beg = offs[v], end = offs[v + 1];
            float ax = 0.f, ay = 0.f, az = 0.f, aw = 0.f;
            int e = beg;
            for (; e + 1 < end; e += 2) {           // 2 loads in flight
                int s0 = csr_src[e], s1 = csr_src[e + 1];
                float4 a0 = *reinterpret_cast<const float4*>(x + (size_t)s0 * D + l * 4);
                float4 a1 = *reinterpret_cast<const float4*>(x + (size_t)s1 * D + l * 4);
                ax += a0.x + a1.x; ay += a0.y + a1.y;
                az += a0.z + a1.z; aw += a0.w + a1.w;
            }
            if (e < end) {
                int s0 = csr_src[e];
                float4 a0 = *reinterpret_cast<const float4*>(x + (size_t)s0 * D + l * 4);
                ax += a0.x; ay += a0.y; az += a0.z; aw += a0.w;
            }
            float scale = 1.0f / fmaxf((float)(end - beg), 1.0f);
            as_[(l * 4 + 0) * PAD + rr] = ax * scale;
            as_[(l * 4 + 1) * PAD + rr] = ay * scale;
            as_[(l * 4 + 2) * PAD + rr] = az * scale;
            as_[(l * 4 + 3) * PAD + rr] = aw * scale;
        }
    }
    __syncthreads();

    // ---- phase C: 4x4 register-tile matmul
    int cg = tid & 31;
    int rg = tid >> 5;
    float acc[4][4] = {};

    const float4* wtsv = reinterpret_cast<const float4*>(Wts);
    const float4* wtnv = reinterpret_cast<const float4*>(Wtn);

    #pragma unroll 4
    for (int k = 0; k < D; ++k) {
        float4 xv = *reinterpret_cast<const float4*>(&xs[k * PAD + rg * 4]);
        float4 av = *reinterpret_cast<const float4*>(&as_[k * PAD + rg * 4]);
        float4 ws = wtsv[k * 32 + cg];
        float4 wn = wtnv[k * 32 + cg];
        float xr[4]  = {xv.x, xv.y, xv.z, xv.w};
        float ar[4]  = {av.x, av.y, av.z, av.w};
        float wsr[4] = {ws.x, ws.y, ws.z, ws.w};
        float wnr[4] = {wn.x, wn.y, wn.z, wn.w};
        #pragma unroll
        for (int qq = 0; qq < 4; ++qq)
            #pragma unroll
            for (int cc = 0; cc < 4; ++cc)
                acc[qq][cc] += xr[qq] * wsr[cc] + ar[qq] * wnr[cc];
    }

    float4 bsv = *reinterpret_cast<const float4*>(bs + cg * 4);
    float4 bnv = *reinterpret_cast<const float4*>(bn + cg * 4);
    float bias[4] = {bsv.x + bnv.x, bsv.y + bnv.y, bsv.z + bnv.z, bsv.w + bnv.w};

    #pragma unroll
    for (int qq = 0; qq < 4; ++qq) {
        float4 o;
        o.x = fmaxf(acc[qq][0] + bias[0], 0.0f);
        o.y = fmaxf(acc[qq][1] + bias[1], 0.0f);
        o.z = fmaxf(acc[qq][2] + bias[2], 0.0f);
        o.w = fmaxf(acc[qq][3] + bias[3], 0.0f);
        *reinterpret_cast<float4*>(out + (size_t)(row0 + rg * 4 + qq) * D + cg * 4) = o;
    }
}

// ================= fallback (R2 path) if ws too small =================
__global__ __launch_bounds__(256) void scatter_edges(const float* __restrict__ x,
                                                     const int* __restrict__ src,
                                                     const int* __restrict__ dst,
                                                     float* __restrict__ agg,
                                                     float* __restrict__ deg) {
    long long gid = (long long)blockIdx.x * 256 + threadIdx.x;
    int e = (int)(gid >> 5);
    int q = (int)(gid & 31);
    if (e >= N_EDGES) return;
    int s = src[e];
    int d = dst[e];
    float4 v = *reinterpret_cast<const float4*>(x + (size_t)s * D + q * 4);
    float* a = agg + (size_t)d * D + q * 4;
    unsafeAtomicAdd(a + 0, v.x);
    unsafeAtomicAdd(a + 1, v.y);
    unsafeAtomicAdd(a + 2, v.z);
    unsafeAtomicAdd(a + 3, v.w);
    if (q == 0) unsafeAtomicAdd(deg + d, 1.0f);
}

__global__ __launch_bounds__(256) void fused_sage(const float* __restrict__ x,
                                                  const float* __restrict__ agg,
                                                  const float* __restrict__ deg,
                                                  const float* __restrict__ Wts,
                                                  const float* __restrict__ Wtn,
                                                  const float* __restrict__ bs,
                                                  const float* __restrict__ bn,
                                                  float* __restrict__ out) {
    __shared__ float xs[D * PAD];
    __shared__ float as_[D * PAD];
    int tid = threadIdx.x;
    int row0 = blockIdx.x * RPB;
    int r  = tid >> 3;
    int c0 = (tid & 7) * 4;
    float scale = 1.0f / fmaxf(deg[row0 + r], 1.0f);
    #pragma unroll
    for (int it = 0; it < 4; ++it) {
        int c = c0 + it * 32;
        float4 xv = *reinterpret_cast<const float4*>(x   + (size_t)(row0 + r) * D + c);
        float4 av = *reinterpret_cast<const float4*>(agg + (size_t)(row0 + r) * D + c);
        xs[(c + 0) * PAD + r] = xv.x;  xs[(c + 1) * PAD + r] = xv.y;
        xs[(c + 2) * PAD + r] = xv.z;  xs[(c + 3) * PAD + r] = xv.w;
        as_[(c + 0) * PAD + r] = av.x * scale;  as_[(c + 1) * PAD + r] = av.y * scale;
        as_[(c + 2) * PAD + r] = av.z * scale;  as_[(c + 3) * PAD + r] = av.w * scale;
    }
    __syncthreads();
    int cg = tid & 31;
    int rg = tid >> 5;
    float acc[4][4] = {};
    const float4* wtsv = reinterpret_cast<const float4*>(Wts);
    const float4* wtnv = reinterpret_cast<const float4*>(Wtn);
    #pragma unroll 4
    for (int k = 0; k < D; ++k) {
        float4 xv = *reinterpret_cast<const float4*>(&xs[k * PAD + rg * 4]);
        float4 av = *reinterpret_cast<const float4*>(&as_[k * PAD + rg * 4]);
        float4 ws = wtsv[k * 32 + cg];
        float4 wn = wtnv[k * 32 + cg];
        float xr[4]  = {xv.x, xv.y, xv.z, xv.w};
        float ar[4]  = {av.x, av.y, av.z, av.w};
        float wsr[4] = {ws.x, ws.y, ws.z, ws.w};
        float wnr[4] = {wn.x, wn.y, wn.z, wn.w};
        #pragma unroll
        for (int qq = 0; qq < 4; ++qq)
            #pragma unroll
            for (int cc = 0; cc < 4; ++cc)
                acc[qq][cc] += xr[qq] * wsr[cc] + ar[qq] * wnr[cc];
    }
    float4 bsv = *reinterpret_cast<const float4*>(bs + cg * 4);
    float4 bnv = *reinterpret_cast<const float4*>(bn + cg * 4);
    float bias[4] = {bsv.x + bnv.x, bsv.y + bnv.y, bsv.z + bnv.z, bsv.w + bnv.w};
    #pragma unroll
    for (int qq = 0; qq < 4; ++qq) {
        float4 o;
        o.x = fmaxf(acc[qq][0] + bias[0], 0.0f);
        o.y = fmaxf(acc[qq][1] + bias[1], 0.0f);
        o.z = fmaxf(acc[qq][2] + bias[2], 0.0f);
        o.w = fmaxf(acc[qq][3] + bias[3], 0.0f);
        *reinterpret_cast<float4*>(out + (size_t)(row0 + rg * 4 + qq) * D + cg * 4) = o;
    }
}

extern "C" void kernel_launch(void* const* d_in, const int* in_sizes, int n_in,
                              void* d_out, int out_size, void* d_ws, size_t ws_size,
                              hipStream_t stream) {
    const float* x  = (const float*)d_in[0];
    const int*   ei = (const int*)d_in[1];   // [2][600000]: row0=src, row1=dst
    const float* Ws = (const float*)d_in[2];
    const float* bs = (const float*)d_in[3];
    const float* Wn = (const float*)d_in[4];
    const float* bn = (const float*)d_in[5];
    float* out = (float*)d_out;

    const int* src = ei;
    const int* dst = ei + N_EDGES;

    // CSR-path workspace layout (ints unless noted):
    //   deg/cursor[100000] | offs[100004] | bsum[512] | csr_src[600000] | Wts f32[16384] | Wtn f32[16384]
    size_t need_ints = (size_t)N_NODES + 100004 + 512 + N_EDGES;
    size_t need_bytes = (need_ints + 2u * D * D) * 4;

    if (ws_size >= need_bytes) {
        int* deg_cur = (int*)d_ws;
        int* offs    = deg_cur + N_NODES;
        int* bsum    = offs + 100004;
        int* csr     = bsum + 512;
        float* Wts   = (float*)(csr + N_EDGES);
        float* Wtn   = Wts + D * D;

        hipMemsetAsync(deg_cur, 0, N_NODES * sizeof(int), stream);
        transpose_w<<<(D * D) / 256, 256, 0, stream>>>(Ws, Wn, Wts, Wtn);
        count_deg<<<(N_EDGES + 255) / 256, 256, 0, stream>>>(dst, deg_cur);
        scan1<<<NB1, SCAN_BLK, 0, stream>>>(deg_cur, offs, bsum);
        scan2<<<1, 512, 0, stream>>>(bsum);
        scan3<<<NB1, SCAN_BLK, 0, stream>>>(offs, bsum, deg_cur);   // deg_cur becomes cursor
        fill_csr<<<(N_EDGES + 255) / 256, 256, 0, stream>>>(src, dst, deg_cur, csr);
        fused_sage_csr<<<N_NODES / RPB, 256, 0, stream>>>(x, offs, csr, Wts, Wtn, bs, bn, out);
    } else {
        // R2 fallback: atomic scatter (needs 528 KB)
        float* deg = (float*)d_ws;
        float* Wts = (float*)d_ws + N_NODES;
        float* Wtn = Wts + D * D;
        hipMemsetAsync(d_out, 0, (size_t)N_NODES * D * sizeof(float), stream);
        hipMemsetAsync(deg, 0, N_NODES * sizeof(float), stream);
        transpose_w<<<(D * D) / 256, 256, 0, stream>>>(Ws, Wn, Wts, Wtn);
        scatter_edges<<<(N_EDGES * 32) / 256, 256, 0, stream>>>(x, src, dst, out, deg);
        fused_sage<<<N_NODES / RPB, 256, 0, stream>>>(x, out, deg, Wts, Wtn, bs, bn, out);
    }
}

// Round 5
// 148.991 us; speedup vs baseline: 7.8884x; 1.4868x over previous
//
#include <hip/hip_runtime.h>

#define N_NODES 100000
#define N_EDGES 600000
#define D 128
#define RPB 32      // rows per block (100000/32 = 3125 exact)
#define AK 264      // LDS A-row length in bf16: 256 (x|agg) + 8 pad -> 528B stride, ~2-way banks
#define SCAN_BLK 256
#define NB1 ((N_NODES + SCAN_BLK - 1) / SCAN_BLK)   // 391

typedef __attribute__((ext_vector_type(8))) short short8;   // 8 bf16 = one MFMA A/B frag
typedef __attribute__((ext_vector_type(4))) float f32x4;    // MFMA C/D frag

static __device__ __forceinline__ short f2bf(float f) {     // f32 -> bf16 bits, RNE
    union { float f; unsigned u; } v; v.f = f;
    unsigned r = v.u + 0x7fffu + ((v.u >> 16) & 1u);
    return (short)(r >> 16);
}

// ---- build Wcat bf16 [128][256]: k<128 -> Ws[n][k], k>=128 -> Wn[n][k-128] ----
__global__ __launch_bounds__(256) void convert_w(const float* __restrict__ Ws,
                                                 const float* __restrict__ Wn,
                                                 short* __restrict__ Wcat) {
    int t = blockIdx.x * 256 + threadIdx.x;      // 0..32767
    int n = t >> 8;
    int k = t & 255;
    float v = (k < D) ? Ws[n * D + k] : Wn[n * D + (k - D)];
    Wcat[t] = f2bf(v);
}

// ================= CSR build =================
__global__ __launch_bounds__(256) void count_deg(const int* __restrict__ dst,
                                                 int* __restrict__ deg) {
    int e = blockIdx.x * 256 + threadIdx.x;
    if (e < N_EDGES) atomicAdd(&deg[dst[e]], 1);
}

__global__ __launch_bounds__(SCAN_BLK) void scan1(const int* __restrict__ deg,
                                                  int* __restrict__ offs,
                                                  int* __restrict__ bsum) {
    __shared__ int sh[SCAN_BLK];
    int t = threadIdx.x;
    int i = blockIdx.x * SCAN_BLK + t;
    int v = (i < N_NODES) ? deg[i] : 0;
    sh[t] = v;
    __syncthreads();
    for (int off = 1; off < SCAN_BLK; off <<= 1) {
        int add = (t >= off) ? sh[t - off] : 0;
        __syncthreads();
        sh[t] += add;
        __syncthreads();
    }
    if (i < N_NODES) offs[i] = sh[t] - v;
    if (t == SCAN_BLK - 1) bsum[blockIdx.x] = sh[t];
}

__global__ __launch_bounds__(512) void scan2(int* __restrict__ bsum) {
    __shared__ int sh[512];
    int t = threadIdx.x;
    int v = (t < NB1) ? bsum[t] : 0;
    sh[t] = v;
    __syncthreads();
    for (int off = 1; off < 512; off <<= 1) {
        int add = (t >= off) ? sh[t - off] : 0;
        __syncthreads();
        sh[t] += add;
        __syncthreads();
    }
    if (t < NB1) bsum[t] = sh[t] - v;
}

__global__ __launch_bounds__(SCAN_BLK) void scan3(int* __restrict__ offs,
                                                  const int* __restrict__ bsum,
                                                  int* __restrict__ cursor) {
    int i = blockIdx.x * SCAN_BLK + threadIdx.x;
    if (i < N_NODES) {
        int o = offs[i] + bsum[blockIdx.x];
        offs[i] = o;
        cursor[i] = o;
    }
    if (i == 0) offs[N_NODES] = N_EDGES;
}

__global__ __launch_bounds__(256) void fill_csr(const int* __restrict__ src,
                                                const int* __restrict__ dst,
                                                int* __restrict__ cursor,
                                                int* __restrict__ csr_src) {
    int e = blockIdx.x * 256 + threadIdx.x;
    if (e < N_EDGES) {
        int pos = atomicAdd(&cursor[dst[e]], 1);
        csr_src[pos] = src[e];
    }
}

// ================= fused: gather-mean -> bf16 A-tile -> MFMA -> bias+relu =================
__global__ __launch_bounds__(256, 4) void fused_sage_mfma(const float* __restrict__ x,
                                                          const int* __restrict__ offs,
                                                          const int* __restrict__ csr_src,
                                                          const short* __restrict__ Wcat,
                                                          const float* __restrict__ bs,
                                                          const float* __restrict__ bn,
                                                          float* __restrict__ out) {
    __shared__ short As[RPB][AK];   // [32 rows][k: 0..127 = x, 128..255 = mean-agg]

    int tid = threadIdx.x;
    int row0 = blockIdx.x * RPB;

    // ---- phase A: stage x rows as bf16 (thread: row tid>>3, 16 cols at (tid&7)*16)
    {
        int r = tid >> 3;
        int c = (tid & 7) * 16;
        const float4* xp = reinterpret_cast<const float4*>(x + (size_t)(row0 + r) * D + c);
        float4 v0 = xp[0], v1 = xp[1], v2 = xp[2], v3 = xp[3];
        short8 p0, p1;
        p0[0] = f2bf(v0.x); p0[1] = f2bf(v0.y); p0[2] = f2bf(v0.z); p0[3] = f2bf(v0.w);
        p0[4] = f2bf(v1.x); p0[5] = f2bf(v1.y); p0[6] = f2bf(v1.z); p0[7] = f2bf(v1.w);
        p1[0] = f2bf(v2.x); p1[1] = f2bf(v2.y); p1[2] = f2bf(v2.z); p1[3] = f2bf(v2.w);
        p1[4] = f2bf(v3.x); p1[5] = f2bf(v3.y); p1[6] = f2bf(v3.z); p1[7] = f2bf(v3.w);
        *reinterpret_cast<short8*>(&As[r][c])     = p0;
        *reinterpret_cast<short8*>(&As[r][c + 8]) = p1;
    }

    // ---- phase B: gather-mean neighbors (half-wave per row, 4 loads in flight)
    {
        int hw = tid >> 5;
        int l  = tid & 31;
        #pragma unroll
        for (int i = 0; i < 4; ++i) {
            int rr = hw * 4 + i;
            int v  = row0 + rr;
            int beg = offs[v], end = offs[v + 1];
            float ax = 0.f, ay = 0.f, az = 0.f, aw = 0.f;
            int e = beg;
            for (; e + 3 < end; e += 4) {
                int s0 = csr_src[e], s1 = csr_src[e + 1], s2 = csr_src[e + 2], s3 = csr_src[e + 3];
                float4 a0 = *reinterpret_cast<const float4*>(x + (size_t)s0 * D + l * 4);
                float4 a1 = *reinterpret_cast<const float4*>(x + (size_t)s1 * D + l * 4);
                float4 a2 = *reinterpret_cast<const float4*>(x + (size_t)s2 * D + l * 4);
                float4 a3 = *reinterpret_cast<const float4*>(x + (size_t)s3 * D + l * 4);
                ax += (a0.x + a1.x) + (a2.x + a3.x);
                ay += (a0.y + a1.y) + (a2.y + a3.y);
                az += (a0.z + a1.z) + (a2.z + a3.z);
                aw += (a0.w + a1.w) + (a2.w + a3.w);
            }
            for (; e < end; ++e) {
                int s0 = csr_src[e];
                float4 a0 = *reinterpret_cast<const float4*>(x + (size_t)s0 * D + l * 4);
                ax += a0.x; ay += a0.y; az += a0.z; aw += a0.w;
            }
            float sc = 1.0f / fmaxf((float)(end - beg), 1.0f);
            unsigned lo = (unsigned short)f2bf(ax * sc) | ((unsigned)(unsigned short)f2bf(ay * sc) << 16);
            unsigned hi = (unsigned short)f2bf(az * sc) | ((unsigned)(unsigned short)f2bf(aw * sc) << 16);
            *reinterpret_cast<uint2*>(&As[rr][D + l * 4]) = make_uint2(lo, hi);
        }
    }
    __syncthreads();

    // ---- phase C: MFMA. wave w -> cols [w*32, w*32+32), all 32 rows. K=256.
    {
        int wv = tid >> 6;
        int l  = tid & 63;
        int lr = l & 15;            // row (A) / col (B) within 16-tile
        int lk = (l >> 4) * 8;      // k offset within 32-block
        int n0 = wv * 32;

        f32x4 acc[2][2] = {};       // [m-tile][n-tile]
        #pragma unroll
        for (int kb = 0; kb < 8; ++kb) {
            short8 a0 = *reinterpret_cast<const short8*>(&As[lr][kb * 32 + lk]);
            short8 a1 = *reinterpret_cast<const short8*>(&As[16 + lr][kb * 32 + lk]);
            #pragma unroll
            for (int nt = 0; nt < 2; ++nt) {
                short8 b = *reinterpret_cast<const short8*>(
                    Wcat + (size_t)(n0 + nt * 16 + lr) * 256 + kb * 32 + lk);
                acc[0][nt] = __builtin_amdgcn_mfma_f32_16x16x32_bf16(a0, b, acc[0][nt], 0, 0, 0);
                acc[1][nt] = __builtin_amdgcn_mfma_f32_16x16x32_bf16(a1, b, acc[1][nt], 0, 0, 0);
            }
        }

        int lq = (l >> 4) * 4;      // C/D row-quad base (m89-verified layout)
        #pragma unroll
        for (int nt = 0; nt < 2; ++nt) {
            int col = n0 + nt * 16 + lr;
            float bias = bs[col] + bn[col];
            #pragma unroll
            for (int mt = 0; mt < 2; ++mt) {
                #pragma unroll
                for (int j = 0; j < 4; ++j) {
                    int row = row0 + mt * 16 + lq + j;
                    out[(size_t)row * D + col] = fmaxf(acc[mt][nt][j] + bias, 0.0f);
                }
            }
        }
    }
}

extern "C" void kernel_launch(void* const* d_in, const int* in_sizes, int n_in,
                              void* d_out, int out_size, void* d_ws, size_t ws_size,
                              hipStream_t stream) {
    const float* x  = (const float*)d_in[0];
    const int*   ei = (const int*)d_in[1];   // [2][600000]: row0=src, row1=dst
    const float* Ws = (const float*)d_in[2];
    const float* bs = (const float*)d_in[3];
    const float* Wn = (const float*)d_in[4];
    const float* bn = (const float*)d_in[5];
    float* out = (float*)d_out;

    const int* src = ei;
    const int* dst = ei + N_EDGES;

    // ws layout: deg/cursor[100000] int | offs[100004] | bsum[512] | csr[600000] | Wcat bf16[32768]
    int* deg_cur = (int*)d_ws;
    int* offs    = deg_cur + N_NODES;
    int* bsum    = offs + 100004;
    int* csr     = bsum + 512;
    short* Wcat  = (short*)(csr + N_EDGES);   // 3,202,064B offset: 16B aligned

    hipMemsetAsync(deg_cur, 0, N_NODES * sizeof(int), stream);
    convert_w<<<128, 256, 0, stream>>>(Ws, Wn, Wcat);
    count_deg<<<(N_EDGES + 255) / 256, 256, 0, stream>>>(dst, deg_cur);
    scan1<<<NB1, SCAN_BLK, 0, stream>>>(deg_cur, offs, bsum);
    scan2<<<1, 512, 0, stream>>>(bsum);
    scan3<<<NB1, SCAN_BLK, 0, stream>>>(offs, bsum, deg_cur);   // deg_cur becomes cursor
    fill_csr<<<(N_EDGES + 255) / 256, 256, 0, stream>>>(src, dst, deg_cur, csr);
    fused_sage_mfma<<<N_NODES / RPB, 256, 0, stream>>>(x, offs, csr, Wcat, bs, bn, out);
}

// Round 6
// 133.395 us; speedup vs baseline: 8.8107x; 1.1169x over previous
//
#include <hip/hip_runtime.h>

#define N_NODES 100000
#define N_EDGES 600000
#define D 128
#define RPB 32      // rows per block (100000/32 = 3125 exact)
#define AK 264      // LDS A-row length in bf16: 256 (x|agg) + 8 pad
#define SCAN_BLK 256
#define NB1 ((N_NODES + SCAN_BLK - 1) / SCAN_BLK)   // 391

typedef __attribute__((ext_vector_type(8))) short short8;   // 8 bf16 = one MFMA A/B frag
typedef __attribute__((ext_vector_type(4))) float f32x4;    // MFMA C/D frag

static __device__ __forceinline__ short f2bf(float f) {     // f32 -> bf16 bits, RNE
    union { float f; unsigned u; } v; v.f = f;
    unsigned r = v.u + 0x7fffu + ((v.u >> 16) & 1u);
    return (short)(r >> 16);
}
static __device__ __forceinline__ float bf2f(short s) {
    union { unsigned u; float f; } c; c.u = ((unsigned)(unsigned short)s) << 16; return c.f;
}

// ---- init: x->bf16, W->bf16 concat, degree histogram. x_bf==nullptr skips convert. ----
__global__ __launch_bounds__(256) void init_all(const float* __restrict__ x,
                                                const float* __restrict__ Ws,
                                                const float* __restrict__ Wn,
                                                const int* __restrict__ dst,
                                                short* __restrict__ x_bf,
                                                short* __restrict__ Wcat,
                                                int* __restrict__ deg) {
    int t = blockIdx.x * 256 + threadIdx.x;          // grid: 6250*256 = 1.6M
    if (x_bf != nullptr && t < (N_NODES * D) / 8) {
        const float4* xp = reinterpret_cast<const float4*>(x + (size_t)t * 8);
        float4 v0 = xp[0], v1 = xp[1];
        short8 p;
        p[0] = f2bf(v0.x); p[1] = f2bf(v0.y); p[2] = f2bf(v0.z); p[3] = f2bf(v0.w);
        p[4] = f2bf(v1.x); p[5] = f2bf(v1.y); p[6] = f2bf(v1.z); p[7] = f2bf(v1.w);
        *reinterpret_cast<short8*>(x_bf + (size_t)t * 8) = p;
    }
    if (t < N_EDGES) atomicAdd(&deg[dst[t]], 1);
    if (t < 2 * D * D) {
        int n = t >> 8, k = t & 255;
        float v = (k < D) ? Ws[n * D + k] : Wn[n * D + (k - D)];
        Wcat[t] = f2bf(v);
    }
}

// ================= CSR build =================
__global__ __launch_bounds__(SCAN_BLK) void scan1(const int* __restrict__ deg,
                                                  int* __restrict__ offs,
                                                  int* __restrict__ bsum) {
    __shared__ int sh[SCAN_BLK];
    int t = threadIdx.x;
    int i = blockIdx.x * SCAN_BLK + t;
    int v = (i < N_NODES) ? deg[i] : 0;
    sh[t] = v;
    __syncthreads();
    for (int off = 1; off < SCAN_BLK; off <<= 1) {
        int add = (t >= off) ? sh[t - off] : 0;
        __syncthreads();
        sh[t] += add;
        __syncthreads();
    }
    if (i < N_NODES) offs[i] = sh[t] - v;
    if (t == SCAN_BLK - 1) bsum[blockIdx.x] = sh[t];
}

// finalize offsets (block computes its own bsum prefix); init cursor (aliases deg)
__global__ __launch_bounds__(SCAN_BLK) void scan3f(int* __restrict__ offs,
                                                   const int* __restrict__ bsum,
                                                   int* __restrict__ cursor) {
    __shared__ int sh[SCAN_BLK];
    int t = threadIdx.x;
    int b = blockIdx.x;
    int s = 0;
    for (int j = t; j < b; j += SCAN_BLK) s += bsum[j];
    sh[t] = s;
    __syncthreads();
    for (int off = SCAN_BLK / 2; off > 0; off >>= 1) {
        if (t < off) sh[t] += sh[t + off];
        __syncthreads();
    }
    int prefix = sh[0];
    int i = b * SCAN_BLK + t;
    if (i < N_NODES) {
        int o = offs[i] + prefix;
        offs[i] = o;
        cursor[i] = o;
    }
    if (b == 0 && t == 0) offs[N_NODES] = N_EDGES;
}

__global__ __launch_bounds__(256) void fill_csr(const int* __restrict__ src,
                                                const int* __restrict__ dst,
                                                int* __restrict__ cursor,
                                                int* __restrict__ csr_src) {
    int e = blockIdx.x * 256 + threadIdx.x;
    if (e < N_EDGES) {
        int pos = atomicAdd(&cursor[dst[e]], 1);
        csr_src[pos] = src[e];
    }
}

// ================= fused (bf16 gather): mean -> A-tile -> MFMA -> bias+relu =================
__global__ __launch_bounds__(256, 4) void fused_sage_bf(const short* __restrict__ x_bf,
                                                        const int* __restrict__ offs,
                                                        const int* __restrict__ csr_src,
                                                        const short* __restrict__ Wcat,
                                                        const float* __restrict__ bs,
                                                        const float* __restrict__ bn,
                                                        float* __restrict__ out) {
    __shared__ short As[RPB][AK];   // [32 rows][k: 0..127 = x, 128..255 = mean-agg]

    int tid = threadIdx.x;
    int row0 = blockIdx.x * RPB;

    // ---- phase A: stage x rows (already bf16)
    {
        int r = tid >> 3;
        int c = (tid & 7) * 16;
        const short8* xp = reinterpret_cast<const short8*>(x_bf + (size_t)(row0 + r) * D + c);
        *reinterpret_cast<short8*>(&As[r][c])     = xp[0];
        *reinterpret_cast<short8*>(&As[r][c + 8]) = xp[1];
    }

    // ---- phase B: gather-mean neighbors. 16 lanes/row (8 bf16 feats per lane), 4-deep loads.
    {
        int g = tid >> 4;       // group 0..15
        int l = tid & 15;       // lane-in-group; feats l*8..l*8+7
        #pragma unroll
        for (int i = 0; i < 2; ++i) {
            int rr = g * 2 + i;
            int v  = row0 + rr;
            int beg = offs[v], end = offs[v + 1];
            float acc[8] = {};
            int e = beg;
            for (; e + 3 < end; e += 4) {
                int s0 = csr_src[e], s1 = csr_src[e + 1], s2 = csr_src[e + 2], s3 = csr_src[e + 3];
                short8 a0 = *reinterpret_cast<const short8*>(x_bf + (size_t)s0 * D + l * 8);
                short8 a1 = *reinterpret_cast<const short8*>(x_bf + (size_t)s1 * D + l * 8);
                short8 a2 = *reinterpret_cast<const short8*>(x_bf + (size_t)s2 * D + l * 8);
                short8 a3 = *reinterpret_cast<const short8*>(x_bf + (size_t)s3 * D + l * 8);
                #pragma unroll
                for (int j = 0; j < 8; ++j)
                    acc[j] += (bf2f(a0[j]) + bf2f(a1[j])) + (bf2f(a2[j]) + bf2f(a3[j]));
            }
            for (; e < end; ++e) {
                int s0 = csr_src[e];
                short8 a0 = *reinterpret_cast<const short8*>(x_bf + (size_t)s0 * D + l * 8);
                #pragma unroll
                for (int j = 0; j < 8; ++j) acc[j] += bf2f(a0[j]);
            }
            float sc = 1.0f / fmaxf((float)(end - beg), 1.0f);
            short8 p;
            #pragma unroll
            for (int j = 0; j < 8; ++j) p[j] = f2bf(acc[j] * sc);
            *reinterpret_cast<short8*>(&As[rr][D + l * 8]) = p;
        }
    }
    __syncthreads();

    // ---- phase C: MFMA. wave w -> cols [w*32, w*32+32), all 32 rows. K=256.
    {
        int wv = tid >> 6;
        int l  = tid & 63;
        int lr = l & 15;
        int lk = (l >> 4) * 8;
        int n0 = wv * 32;

        f32x4 acc[2][2] = {};
        #pragma unroll
        for (int kb = 0; kb < 8; ++kb) {
            short8 a0 = *reinterpret_cast<const short8*>(&As[lr][kb * 32 + lk]);
            short8 a1 = *reinterpret_cast<const short8*>(&As[16 + lr][kb * 32 + lk]);
            #pragma unroll
            for (int nt = 0; nt < 2; ++nt) {
                short8 b = *reinterpret_cast<const short8*>(
                    Wcat + (size_t)(n0 + nt * 16 + lr) * 256 + kb * 32 + lk);
                acc[0][nt] = __builtin_amdgcn_mfma_f32_16x16x32_bf16(a0, b, acc[0][nt], 0, 0, 0);
                acc[1][nt] = __builtin_amdgcn_mfma_f32_16x16x32_bf16(a1, b, acc[1][nt], 0, 0, 0);
            }
        }

        int lq = (l >> 4) * 4;
        #pragma unroll
        for (int nt = 0; nt < 2; ++nt) {
            int col = n0 + nt * 16 + lr;
            float bias = bs[col] + bn[col];
            #pragma unroll
            for (int mt = 0; mt < 2; ++mt) {
                #pragma unroll
                for (int j = 0; j < 4; ++j) {
                    int row = row0 + mt * 16 + lq + j;
                    out[(size_t)row * D + col] = fmaxf(acc[mt][nt][j] + bias, 0.0f);
                }
            }
        }
    }
}

// ================= fallback fused (f32 gather, R5-proven) =================
__global__ __launch_bounds__(256, 4) void fused_sage_f32(const float* __restrict__ x,
                                                         const int* __restrict__ offs,
                                                         const int* __restrict__ csr_src,
                                                         const short* __restrict__ Wcat,
                                                         const float* __restrict__ bs,
                                                         const float* __restrict__ bn,
                                                         float* __restrict__ out) {
    __shared__ short As[RPB][AK];
    int tid = threadIdx.x;
    int row0 = blockIdx.x * RPB;
    {
        int r = tid >> 3;
        int c = (tid & 7) * 16;
        const float4* xp = reinterpret_cast<const float4*>(x + (size_t)(row0 + r) * D + c);
        float4 v0 = xp[0], v1 = xp[1], v2 = xp[2], v3 = xp[3];
        short8 p0, p1;
        p0[0] = f2bf(v0.x); p0[1] = f2bf(v0.y); p0[2] = f2bf(v0.z); p0[3] = f2bf(v0.w);
        p0[4] = f2bf(v1.x); p0[5] = f2bf(v1.y); p0[6] = f2bf(v1.z); p0[7] = f2bf(v1.w);
        p1[0] = f2bf(v2.x); p1[1] = f2bf(v2.y); p1[2] = f2bf(v2.z); p1[3] = f2bf(v2.w);
        p1[4] = f2bf(v3.x); p1[5] = f2bf(v3.y); p1[6] = f2bf(v3.z); p1[7] = f2bf(v3.w);
        *reinterpret_cast<short8*>(&As[r][c])     = p0;
        *reinterpret_cast<short8*>(&As[r][c + 8]) = p1;
    }
    {
        int hw = tid >> 5;
        int l  = tid & 31;
        #pragma unroll
        for (int i = 0; i < 4; ++i) {
            int rr = hw * 4 + i;
            int v  = row0 + rr;
            int beg = offs[v], end = offs[v + 1];
            float ax = 0.f, ay = 0.f, az = 0.f, aw = 0.f;
            int e = beg;
            for (; e + 3 < end; e += 4) {
                int s0 = csr_src[e], s1 = csr_src[e + 1], s2 = csr_src[e + 2], s3 = csr_src[e + 3];
                float4 a0 = *reinterpret_cast<const float4*>(x + (size_t)s0 * D + l * 4);
                float4 a1 = *reinterpret_cast<const float4*>(x + (size_t)s1 * D + l * 4);
                float4 a2 = *reinterpret_cast<const float4*>(x + (size_t)s2 * D + l * 4);
                float4 a3 = *reinterpret_cast<const float4*>(x + (size_t)s3 * D + l * 4);
                ax += (a0.x + a1.x) + (a2.x + a3.x);
                ay += (a0.y + a1.y) + (a2.y + a3.y);
                az += (a0.z + a1.z) + (a2.z + a3.z);
                aw += (a0.w + a1.w) + (a2.w + a3.w);
            }
            for (; e < end; ++e) {
                int s0 = csr_src[e];
                float4 a0 = *reinterpret_cast<const float4*>(x + (size_t)s0 * D + l * 4);
                ax += a0.x; ay += a0.y; az += a0.z; aw += a0.w;
            }
            float sc = 1.0f / fmaxf((float)(end - beg), 1.0f);
            unsigned lo = (unsigned short)f2bf(ax * sc) | ((unsigned)(unsigned short)f2bf(ay * sc) << 16);
            unsigned hi = (unsigned short)f2bf(az * sc) | ((unsigned)(unsigned short)f2bf(aw * sc) << 16);
            *reinterpret_cast<uint2*>(&As[rr][D + l * 4]) = make_uint2(lo, hi);
        }
    }
    __syncthreads();
    {
        int wv = tid >> 6;
        int l  = tid & 63;
        int lr = l & 15;
        int lk = (l >> 4) * 8;
        int n0 = wv * 32;
        f32x4 acc[2][2] = {};
        #pragma unroll
        for (int kb = 0; kb < 8; ++kb) {
            short8 a0 = *reinterpret_cast<const short8*>(&As[lr][kb * 32 + lk]);
            short8 a1 = *reinterpret_cast<const short8*>(&As[16 + lr][kb * 32 + lk]);
            #pragma unroll
            for (int nt = 0; nt < 2; ++nt) {
                short8 b = *reinterpret_cast<const short8*>(
                    Wcat + (size_t)(n0 + nt * 16 + lr) * 256 + kb * 32 + lk);
                acc[0][nt] = __builtin_amdgcn_mfma_f32_16x16x32_bf16(a0, b, acc[0][nt], 0, 0, 0);
                acc[1][nt] = __builtin_amdgcn_mfma_f32_16x16x32_bf16(a1, b, acc[1][nt], 0, 0, 0);
            }
        }
        int lq = (l >> 4) * 4;
        #pragma unroll
        for (int nt = 0; nt < 2; ++nt) {
            int col = n0 + nt * 16 + lr;
            float bias = bs[col] + bn[col];
            #pragma unroll
            for (int mt = 0; mt < 2; ++mt) {
                #pragma unroll
                for (int j = 0; j < 4; ++j) {
                    int row = row0 + mt * 16 + lq + j;
                    out[(size_t)row * D + col] = fmaxf(acc[mt][nt][j] + bias, 0.0f);
                }
            }
        }
    }
}

extern "C" void kernel_launch(void* const* d_in, const int* in_sizes, int n_in,
                              void* d_out, int out_size, void* d_ws, size_t ws_size,
                              hipStream_t stream) {
    const float* x  = (const float*)d_in[0];
    const int*   ei = (const int*)d_in[1];   // [2][600000]: row0=src, row1=dst
    const float* Ws = (const float*)d_in[2];
    const float* bs = (const float*)d_in[3];
    const float* Wn = (const float*)d_in[4];
    const float* bn = (const float*)d_in[5];
    float* out = (float*)d_out;

    const int* src = ei;
    const int* dst = ei + N_EDGES;

    // ws layout: deg/cursor[100000] int | offs[100004] | bsum[512] | csr[600000] int
    //            | Wcat bf16[32768] | x_bf bf16[12800000]
    int* deg_cur = (int*)d_ws;
    int* offs    = deg_cur + N_NODES;
    int* bsum    = offs + 100004;
    int* csr     = bsum + 512;
    short* Wcat  = (short*)(csr + N_EDGES);
    short* x_bf  = Wcat + 2 * D * D;

    size_t need_base = (size_t)(N_NODES + 100004 + 512 + N_EDGES) * 4 + (size_t)2 * D * D * 2;
    size_t need_full = need_base + (size_t)N_NODES * D * 2;
    bool use_bf = (ws_size >= need_full);

    hipMemsetAsync(deg_cur, 0, N_NODES * sizeof(int), stream);
    init_all<<<(N_NODES * D / 8 + 255) / 256, 256, 0, stream>>>(
        x, Ws, Wn, dst, use_bf ? x_bf : nullptr, Wcat, deg_cur);
    scan1<<<NB1, SCAN_BLK, 0, stream>>>(deg_cur, offs, bsum);
    scan3f<<<NB1, SCAN_BLK, 0, stream>>>(offs, bsum, deg_cur);   // deg_cur becomes cursor
    fill_csr<<<(N_EDGES + 255) / 256, 256, 0, stream>>>(src, dst, deg_cur, csr);
    if (use_bf)
        fused_sage_bf<<<N_NODES / RPB, 256, 0, stream>>>(x_bf, offs, csr, Wcat, bs, bn, out);
    else
        fused_sage_f32<<<N_NODES / RPB, 256, 0, stream>>>(x, offs, csr, Wcat, bs, bn, out);
}